// Round 1
// baseline (79.808 us; speedup 1.0000x reference)
//
#include <hip/hip_runtime.h>
#include <math.h>

#define NB 64

struct C { float x, y; };

__device__ __forceinline__ C cmul(C a, C b){ return C{a.x*b.x - a.y*b.y, a.x*b.y + a.y*b.x}; }

// LDS address swizzle to break power-of-2 stride bank conflicts (perf-only, bijective)
__device__ __forceinline__ int SW(int a){ return a ^ ((a>>4)&15); }

// new_j = sum_i x_i * G[i][j]  (reference einsum contracts gate's FIRST index with state)
__device__ __forceinline__ void bfly(C& x0, C& x1, const C* G){
  C n0 = C{x0.x*G[0].x - x0.y*G[0].y + x1.x*G[2].x - x1.y*G[2].y,
           x0.x*G[0].y + x0.y*G[0].x + x1.x*G[2].y + x1.y*G[2].x};
  C n1 = C{x0.x*G[1].x - x0.y*G[1].y + x1.x*G[3].x - x1.y*G[3].y,
           x0.x*G[1].y + x0.y*G[1].x + x1.x*G[3].y + x1.y*G[3].x};
  x0 = n0; x1 = n1;
}

// compact even bits: out bit m = in bit 2m
__device__ __forceinline__ unsigned ceven(unsigned x){
  x &= 0x5555u; x=(x|(x>>1))&0x3333u; x=(x|(x>>2))&0x0F0Fu; x=(x|(x>>4))&0x00FFu; return x;
}

__device__ __forceinline__ int expand44(int t2, int k2){
  int j=0;
  #pragma unroll
  for (int m=0;m<4;m++){ j |= ((t2>>m)&1)<<(2*m); j |= ((k2>>m)&1)<<(2*m+1); }
  return j;
}

// M = Rx(tx)*Ry(ty)*Rz(tz), row-major M[i*2+j]; reference applies new = x^T * M
__device__ void fused_M(float tx, float ty, float tz, C* M){
  float cx=cosf(0.5f*tx), sx=sinf(0.5f*tx);
  float cy=cosf(0.5f*ty), sy=sinf(0.5f*ty);
  float cz=cosf(0.5f*tz), sz=sinf(0.5f*tz);
  // B = Rx*Ry ; Rx=[[cx,-i sx],[-i sx,cx]], Ry=[[cy,-sy],[sy,cy]]
  C b0 = C{ cx*cy, -sx*sy};   // B00
  C b1 = C{-cx*sy, -sx*cy};   // B01
  C b2 = C{ cx*sy, -sx*cy};   // B10
  C b3 = C{ cx*cy,  sx*sy};   // B11
  C e0 = C{cz,-sz}, e1 = C{cz, sz};
  M[0]=cmul(b0,e0); M[1]=cmul(b1,e1);
  M[2]=cmul(b2,e0); M[3]=cmul(b3,e1);
}

// ---------------- device globals (scratch) ----------------
__device__ C     g_lut[NB][512];       // Vh2 [0..255], Vl2 [256..511]
__device__ C     g_M0[16][4];
__device__ C     g_M1[8][4];
__device__ C     g_c7[2];              // boundary ZZ pair (qubits 7,8): [0]=bits equal
__device__ C     g_buf1[NB][65536];
__device__ C     g_buf2[NB][65536];    // (t<<8)|k layout
__device__ float g_ppart[NB][16][64];

// ---------------- K0: angles -> v vectors -> LUTs; fused gate matrices ----------------
__global__ __launch_bounds__(256) void k_prep(const float* __restrict__ nbr,
    const float* __restrict__ slf, const float* __restrict__ Wp,
    const float* __restrict__ bp, const float* __restrict__ rot0,
    const float* __restrict__ zz0, const float* __restrict__ rot1){
  int b = blockIdx.x, tid = threadIdx.x;
  __shared__ float th[48];
  __shared__ C vq[16][2];
  __shared__ float zz0s[15];
  if (tid < 15) zz0s[tid] = zz0[tid];
  if (tid < 48){
    int q = tid/3, c = tid - q*3, g = q>>2, j = (q&3)*3 + c;
    const float* f = (g==0) ? (slf + (size_t)b*128) : (nbr + ((size_t)b*3 + (g-1))*128);
    const float* wrow = Wp + j*128;
    float acc = bp[j];
    for (int d=0; d<128; d++) acc += f[d]*wrow[d];
    th[tid] = acc;
  }
  __syncthreads();
  if (tid < 16){
    C M[4];
    fused_M(th[tid*3+0], th[tid*3+1], th[tid*3+2], M);
    vq[tid][0] = M[0]; vq[tid][1] = M[1];   // row 0: e0^T * Rx*Ry*Rz
  }
  __syncthreads();
  {
    int h = tid; // 0..255
    // high LUT: qubits 0..7 (h bit (7-q)), ZZ pairs 0..6
    C p = vq[0][(h>>7)&1];
    #pragma unroll
    for (int q=1;q<8;q++) p = cmul(p, vq[q][(h>>(7-q))&1]);
    float A = 0.f;
    #pragma unroll
    for (int kk=0;kk<7;kk++){
      int b0=(h>>(7-kk))&1, b1=(h>>(6-kk))&1;
      A += (b0==b1) ? zz0s[kk] : -zz0s[kk];
    }
    float s,c; sincosf(0.5f*A,&s,&c);
    g_lut[b][h] = cmul(p, C{c,-s});
    // low LUT: qubits 8..15 (l bit (15-q)), ZZ pairs 8..14
    C pl = vq[8][(h>>7)&1];
    #pragma unroll
    for (int q=9;q<16;q++) pl = cmul(pl, vq[q][(h>>(15-q))&1]);
    float Al = 0.f;
    #pragma unroll
    for (int kk=8;kk<15;kk++){
      int b0=(h>>(15-kk))&1, b1=(h>>(14-kk))&1;
      Al += (b0==b1) ? zz0s[kk] : -zz0s[kk];
    }
    sincosf(0.5f*Al,&s,&c);
    g_lut[b][256+h] = cmul(pl, C{c,-s});
  }
  if (b == 0){
    if (tid < 16){
      fused_M(rot0[tid*3+0], rot0[tid*3+1], rot0[tid*3+2], &g_M0[tid][0]);
    } else if (tid < 24){
      int q = tid-16;
      fused_M(rot1[q*3+0], rot1[q*3+1], rot1[q*3+2], &g_M1[q][0]);
    } else if (tid == 24){
      float t7 = zz0[7];
      float s,c; sincosf(0.5f*t7,&s,&c);
      g_c7[0] = C{c,-s};  // bits equal
      g_c7[1] = C{c, s};  // bits differ
    }
  }
}

// grouped 3-qubit butterfly pass over LDS bits p0<p1<p2
__device__ void pass3(C* S, int tid, int p0, int p1, int p2,
                      const C* G0, const C* G1, const C* G2, int nAmps){
  int m0=1<<p0, m1=1<<p1, m2=1<<p2;
  for (int bi = tid; bi < (nAmps>>3); bi += 256){
    int x = bi;
    x = ((x>>p0)<<(p0+1)) | (x & (m0-1));
    x = ((x>>p1)<<(p1+1)) | (x & (m1-1));
    x = ((x>>p2)<<(p2+1)) | (x & (m2-1));
    C c0=S[SW(x)],       c1=S[SW(x|m0)],    c2=S[SW(x|m1)],    c3=S[SW(x|m0|m1)];
    C c4=S[SW(x|m2)],    c5=S[SW(x|m0|m2)], c6=S[SW(x|m1|m2)], c7v=S[SW(x|m0|m1|m2)];
    bfly(c0,c1,G0); bfly(c2,c3,G0); bfly(c4,c5,G0); bfly(c6,c7v,G0);
    bfly(c0,c2,G1); bfly(c1,c3,G1); bfly(c4,c6,G1); bfly(c5,c7v,G1);
    bfly(c0,c4,G2); bfly(c1,c5,G2); bfly(c2,c6,G2); bfly(c3,c7v,G2);
    S[SW(x)]=c0;       S[SW(x|m0)]=c1;    S[SW(x|m1)]=c2;    S[SW(x|m0|m1)]=c3;
    S[SW(x|m2)]=c4;    S[SW(x|m0|m2)]=c5; S[SW(x|m1|m2)]=c6; S[SW(x|m0|m1|m2)]=c7v;
  }
}

__device__ void pass1(C* S, int tid, int p, const C* G, int nAmps){
  int m=1<<p;
  for (int bi = tid; bi < (nAmps>>1); bi += 256){
    int x = ((bi>>p)<<(p+1)) | (bi & (m-1));
    C x0=S[SW(x)], x1=S[SW(x|m)];
    bfly(x0,x1,G);
    S[SW(x)]=x0; S[SW(x|m)]=x1;
  }
}

// ---------------- K1: build psi0 (product * ZZ phases), apply gates on qubits 4..15 ----------------
__global__ __launch_bounds__(256) void k_conv0_a(){
  int blk = blockIdx.x, b = blk>>4, T = blk&15, tid = threadIdx.x;
  __shared__ C S[4096];
  __shared__ C Vh[256], Vl[256];
  __shared__ C Mg[12][4];   // qubits 4..15 -> index q-4
  __shared__ C c7s[2];
  Vh[tid] = g_lut[b][tid];
  Vl[tid] = g_lut[b][256+tid];
  if (tid < 48) Mg[tid>>2][tid&3] = g_M0[4+(tid>>2)][tid&3];
  if (tid < 2)  c7s[tid] = g_c7[tid];
  __syncthreads();
  #pragma unroll
  for (int it=0; it<16; ++it){
    int a = it*256 + tid;
    int i = (T<<12) | a;
    C amp = cmul(cmul(Vh[i>>8], Vl[i&255]), c7s[((i>>8)^(i>>7))&1]);
    S[SW(a)] = amp;
  }
  __syncthreads();
  // LDS bit p (=amp bit p) <-> qubit 15-p <-> Mg[11-p]
  pass3(S,tid, 0,1,2,  Mg[11],Mg[10],Mg[9], 4096); __syncthreads();
  pass3(S,tid, 3,4,5,  Mg[8], Mg[7], Mg[6], 4096); __syncthreads();
  pass3(S,tid, 6,7,8,  Mg[5], Mg[4], Mg[3], 4096); __syncthreads();
  pass3(S,tid, 9,10,11,Mg[2], Mg[1], Mg[0], 4096); __syncthreads();
  #pragma unroll
  for (int it=0; it<16; ++it){
    int a = it*256 + tid;
    g_buf1[b][(T<<12)|a] = S[SW(a)];
  }
}

// ---------------- K2: gates on qubits 0..3, pooling partials, (t,k) scatter ----------------
__global__ __launch_bounds__(256) void k_conv0_b(){
  int blk = blockIdx.x, b = blk>>4, T2 = blk&15, tid = threadIdx.x;
  __shared__ C S[4096];
  __shared__ C Mh[4][4];
  __shared__ float pbuf[4][256];
  if (tid < 16) Mh[tid>>2][tid&3] = g_M0[tid>>2][tid&3];
  // LDS addr a: bits[7:0]=i[7:0], bits[11:8]=i[15:12]; tile T2 = i[11:8]
  #pragma unroll
  for (int it=0; it<16; ++it){
    int a = it*256 + tid;
    int i = (it<<12) | (T2<<8) | tid;
    S[SW(a)] = g_buf1[b][i];
  }
  __syncthreads();
  // LDS bit 8,9,10,11 <-> i bit 12,13,14,15 <-> qubits 3,2,1,0
  pass3(S,tid, 8,9,10, Mh[3],Mh[2],Mh[1], 4096); __syncthreads();
  pass1(S,tid, 11, Mh[0], 4096); __syncthreads();
  float pr0=0.f, pr1=0.f, pr2=0.f, pr3=0.f;
  #pragma unroll
  for (int it=0; it<16; ++it){
    int a = it*256 + tid;
    int i = (it<<12) | (T2<<8) | tid;
    C v = S[SW(a)];
    unsigned t = ceven((unsigned)i), k = ceven((unsigned)i>>1);
    g_buf2[b][(t<<8)|k] = v;
    float pw = v.x*v.x + v.y*v.y;
    int slot = (it&1) | (((it>>2)&1)<<1);   // (t6,t7); static under unroll
    if      (slot==0) pr0 += pw;
    else if (slot==1) pr1 += pw;
    else if (slot==2) pr2 += pw;
    else              pr3 += pw;
  }
  pbuf[0][tid]=pr0; pbuf[1][tid]=pr1; pbuf[2][tid]=pr2; pbuf[3][tid]=pr3;
  __syncthreads();
  if (tid < 64){
    int t03 = tid & 15, s = tid>>4;   // bin bits: [3:0]=t0..3, [4]=t6, [5]=t7
    float sum = 0.f;
    #pragma unroll
    for (int j=0;j<16;j++){
      int tp = (t03&1) | ((j&1)<<1) | (((t03>>1)&1)<<2) | (((j>>1)&1)<<3)
             | (((t03>>2)&1)<<4) | (((j>>2)&1)<<5) | (((t03>>3)&1)<<6) | (((j>>3)&1)<<7);
      sum += pbuf[s][tp];
    }
    g_ppart[b][T2][tid] = sum;
  }
}

// ---------------- K4: pool1 weights+reduce, conv1, pool2, measure, output ----------------
__global__ __launch_bounds__(256) void k_tail(const float* __restrict__ zz1,
    const float* __restrict__ Wo, const float* __restrict__ bo,
    float* __restrict__ out){
  int b = blockIdx.x, tid = threadIdx.x;
  __shared__ float w[256], red[256];
  __shared__ C M1s[8][4];
  __shared__ float zz1s[7];
  __shared__ C s8[256];
  __shared__ float p2[16];
  __shared__ C s2[16];
  __shared__ float sc[2];
  __shared__ float zm[4];
  if (tid < 32) M1s[tid>>2][tid&3] = g_M1[tid>>2][tid&3];
  if (tid < 7)  zz1s[tid] = zz1[tid];
  // pool1 probabilities: t = tid
  {
    int t4=(tid>>4)&1, t5=(tid>>5)&1, t6=(tid>>6)&1, t7=(tid>>7)&1;
    int bin = (tid&15) | (t6<<4) | (t7<<5);
    float wr = 0.f;
    #pragma unroll
    for (int k5=0;k5<2;k5++)
      #pragma unroll
      for (int k4=0;k4<2;k4++)
        wr += g_ppart[b][t4 | (k4<<1) | (t5<<2) | (k5<<3)][bin];
    red[tid] = wr;
    w[tid] = wr;
  }
  __syncthreads();
  for (int s=128; s>0; s>>=1){ if (tid<s) red[tid]+=red[tid+s]; __syncthreads(); }
  float tot = red[0];
  __syncthreads();
  w[tid] = sqrtf(w[tid]/(tot + 1e-10f));
  __syncthreads();
  // pooled state s1[k], k = tid
  C acc = C{0.f,0.f};
  #pragma unroll 4
  for (int tt=0; tt<256; ++tt){
    C v = g_buf2[b][(tt<<8)|tid];
    float ww = w[tt];
    acc.x += v.x*ww; acc.y += v.y*ww;
  }
  red[tid] = acc.x*acc.x + acc.y*acc.y;
  __syncthreads();
  for (int s=128; s>0; s>>=1){ if (tid<s) red[tid]+=red[tid+s]; __syncthreads(); }
  float n1 = sqrtf(red[0] + 1e-10f);
  C s1 = C{acc.x/n1, acc.y/n1};
  // conv1 ZZ diagonal (7 adjacent pairs on 8 qubits; qubit q <-> bit 7-q)
  float A = 0.f;
  #pragma unroll
  for (int kk=0;kk<7;kk++){
    int b0=(tid>>(7-kk))&1, b1=(tid>>(6-kk))&1;
    A += (b0==b1) ? zz1s[kk] : -zz1s[kk];
  }
  float sa,ca; sincosf(0.5f*A,&sa,&ca);
  s8[tid] = cmul(s1, C{ca,-sa});
  __syncthreads();
  // conv1 fused gates
  for (int q=0;q<8;q++){
    int p = 7-q, m = 1<<p;
    if ((tid & m) == 0){
      C x0=s8[tid], x1=s8[tid|m];
      bfly(x0,x1,&M1s[q][0]);
      s8[tid]=x0; s8[tid|m]=x1;
    }
    __syncthreads();
  }
  // pool2: t2 = even bits of j, k2 = odd bits
  if (tid < 16){
    float s = 0.f;
    #pragma unroll
    for (int k2=0;k2<16;k2++){ C v=s8[expand44(tid,k2)]; s += v.x*v.x + v.y*v.y; }
    p2[tid] = s;
  }
  __syncthreads();
  if (tid == 0){ float S2=0.f; for (int i2=0;i2<16;i2++) S2+=p2[i2]; sc[0]=S2; }
  __syncthreads();
  if (tid < 16) p2[tid] = sqrtf(p2[tid]/(sc[0]+1e-10f));
  __syncthreads();
  if (tid < 16){
    C a2 = C{0.f,0.f};
    #pragma unroll
    for (int t2=0;t2<16;t2++){ C v=s8[expand44(t2,tid)]; float ww=p2[t2]; a2.x+=v.x*ww; a2.y+=v.y*ww; }
    s2[tid] = a2;
  }
  __syncthreads();
  if (tid == 0){
    float nn=0.f; for (int i2=0;i2<16;i2++) nn += s2[i2].x*s2[i2].x + s2[i2].y*s2[i2].y;
    sc[1] = nn + 1e-10f;
  }
  __syncthreads();
  // measure_z on 4 qubits (qubit q <-> bit 3-q)
  if (tid < 4){
    float z = 0.f;
    #pragma unroll
    for (int idx=0; idx<16; idx++){
      C v = s2[idx];
      float pr = (v.x*v.x + v.y*v.y)/sc[1];
      z += ((idx>>(3-tid))&1) ? -pr : pr;
    }
    zm[tid] = z;
  }
  __syncthreads();
  if (tid < 64){
    float r = bo[tid];
    #pragma unroll
    for (int q=0;q<4;q++) r += zm[q]*Wo[tid*4+q];
    out[(size_t)b*64 + tid] = r;
  }
}

extern "C" void kernel_launch(void* const* d_in, const int* in_sizes, int n_in,
                              void* d_out, int out_size, void* d_ws, size_t ws_size,
                              hipStream_t stream) {
  const float* nbr  = (const float*)d_in[0];
  const float* slf  = (const float*)d_in[1];
  const float* Wp   = (const float*)d_in[2];
  const float* bp   = (const float*)d_in[3];
  const float* rot0 = (const float*)d_in[4];
  const float* zz0  = (const float*)d_in[5];
  const float* rot1 = (const float*)d_in[6];
  const float* zz1  = (const float*)d_in[7];
  const float* Wo   = (const float*)d_in[8];
  const float* bo   = (const float*)d_in[9];
  float* out = (float*)d_out;

  hipLaunchKernelGGL(k_prep,    dim3(NB),   dim3(256), 0, stream, nbr, slf, Wp, bp, rot0, zz0, rot1);
  hipLaunchKernelGGL(k_conv0_a, dim3(NB*16),dim3(256), 0, stream);
  hipLaunchKernelGGL(k_conv0_b, dim3(NB*16),dim3(256), 0, stream);
  hipLaunchKernelGGL(k_tail,    dim3(NB),   dim3(256), 0, stream, zz1, Wo, bo, out);
}

// Round 2
// 79.304 us; speedup vs baseline: 1.0064x; 1.0064x over previous
//
#include <hip/hip_runtime.h>
#include <hip/hip_cooperative_groups.h>
#include <math.h>

namespace cg = cooperative_groups;

#define NB 64

struct C { float x, y; };

__device__ __forceinline__ C cmul(C a, C b){ return C{a.x*b.x - a.y*b.y, a.x*b.y + a.y*b.x}; }

// LDS address swizzles (bijective, perf-only)
__device__ __forceinline__ int SW(int a){ return a ^ ((a>>4)&15); }
__device__ __forceinline__ int SW2(int a){ return a ^ ((a>>8)&7); }

// new_j = sum_i x_i * G[i][j]  (reference einsum contracts gate's FIRST index with state)
__device__ __forceinline__ void bfly(C& x0, C& x1, const C* G){
  C n0 = C{x0.x*G[0].x - x0.y*G[0].y + x1.x*G[2].x - x1.y*G[2].y,
           x0.x*G[0].y + x0.y*G[0].x + x1.x*G[2].y + x1.y*G[2].x};
  C n1 = C{x0.x*G[1].x - x0.y*G[1].y + x1.x*G[3].x - x1.y*G[3].y,
           x0.x*G[1].y + x0.y*G[1].x + x1.x*G[3].y + x1.y*G[3].x};
  x0 = n0; x1 = n1;
}

__device__ __forceinline__ unsigned ceven(unsigned x){
  x &= 0x5555u; x=(x|(x>>1))&0x3333u; x=(x|(x>>2))&0x0F0Fu; x=(x|(x>>4))&0x00FFu; return x;
}

__device__ __forceinline__ int expand44(int t2, int k2){
  int j=0;
  #pragma unroll
  for (int m=0;m<4;m++){ j |= ((t2>>m)&1)<<(2*m); j |= ((k2>>m)&1)<<(2*m+1); }
  return j;
}

// M = Rx(tx)*Ry(ty)*Rz(tz), row-major M[i*2+j]; reference applies new = x^T * M
__device__ void fused_M(float tx, float ty, float tz, C* M){
  float cx=cosf(0.5f*tx), sx=sinf(0.5f*tx);
  float cy=cosf(0.5f*ty), sy=sinf(0.5f*ty);
  float cz=cosf(0.5f*tz), sz=sinf(0.5f*tz);
  C b0 = C{ cx*cy, -sx*sy};
  C b1 = C{-cx*sy, -sx*cy};
  C b2 = C{ cx*sy, -sx*cy};
  C b3 = C{ cx*cy,  sx*sy};
  C e0 = C{cz,-sz}, e1 = C{cz, sz};
  M[0]=cmul(b0,e0); M[1]=cmul(b1,e1);
  M[2]=cmul(b2,e0); M[3]=cmul(b3,e1);
}

// ---------------- device globals (scratch) ----------------
__device__ C     g_lut[NB][512];
__device__ C     g_M0[16][4];
__device__ C     g_M1[8][4];
__device__ C     g_c7[2];
__device__ C     g_buf1[NB][65536];
__device__ C     g_buf2[NB][65536];
__device__ float g_ppart[NB][16][64];
__device__ C     g_s1p[NB][16][64];

// grouped 3-qubit butterfly pass over LDS bits p0<p1<p2
__device__ void pass3(C* S, int tid, int p0, int p1, int p2,
                      const C* G0, const C* G1, const C* G2, int nAmps){
  int m0=1<<p0, m1=1<<p1, m2=1<<p2;
  for (int bi = tid; bi < (nAmps>>3); bi += 256){
    int x = bi;
    x = ((x>>p0)<<(p0+1)) | (x & (m0-1));
    x = ((x>>p1)<<(p1+1)) | (x & (m1-1));
    x = ((x>>p2)<<(p2+1)) | (x & (m2-1));
    C c0=S[SW(x)],       c1=S[SW(x|m0)],    c2=S[SW(x|m1)],    c3=S[SW(x|m0|m1)];
    C c4=S[SW(x|m2)],    c5=S[SW(x|m0|m2)], c6=S[SW(x|m1|m2)], c7v=S[SW(x|m0|m1|m2)];
    bfly(c0,c1,G0); bfly(c2,c3,G0); bfly(c4,c5,G0); bfly(c6,c7v,G0);
    bfly(c0,c2,G1); bfly(c1,c3,G1); bfly(c4,c6,G1); bfly(c5,c7v,G1);
    bfly(c0,c4,G2); bfly(c1,c5,G2); bfly(c2,c6,G2); bfly(c3,c7v,G2);
    S[SW(x)]=c0;       S[SW(x|m0)]=c1;    S[SW(x|m1)]=c2;    S[SW(x|m0|m1)]=c3;
    S[SW(x|m2)]=c4;    S[SW(x|m0|m2)]=c5; S[SW(x|m1|m2)]=c6; S[SW(x|m0|m1|m2)]=c7v;
  }
}

__device__ void pass1(C* S, int tid, int p, const C* G, int nAmps){
  int m=1<<p;
  for (int bi = tid; bi < (nAmps>>1); bi += 256){
    int x = ((bi>>p)<<(p+1)) | (bi & (m-1));
    C x0=S[SW(x)], x1=S[SW(x|m)];
    bfly(x0,x1,G);
    S[SW(x)]=x0; S[SW(x|m)]=x1;
  }
}

// ================= FUSED COOPERATIVE KERNEL =================
__global__ __launch_bounds__(256, 4) void k_fused(
    const float* __restrict__ nbr, const float* __restrict__ slf,
    const float* __restrict__ Wp, const float* __restrict__ bp,
    const float* __restrict__ rot0, const float* __restrict__ zz0,
    const float* __restrict__ rot1, const float* __restrict__ zz1,
    const float* __restrict__ Wo, const float* __restrict__ bo,
    float* __restrict__ out)
{
  cg::grid_group grid = cg::this_grid();
  const int blk = blockIdx.x, tid = threadIdx.x;
  const int b = blk >> 4, T = blk & 15;

  __shared__ union BigU {
    C S[4096];                                   // 32 KB (phases B,C,D)
    struct {                                     // phase E
      C s8[256]; float redE[256]; C M1s[8][4];
      float zz1s[7]; float p2[16]; C s2[16]; float sc[2]; float zm[4];
    } e;
  } big;
  __shared__ union SmallU {
    struct { C Vh[256]; C Vl[256]; } lut;        // 4 KB
    float thp[48][4];
    float pbuf[64][17];
    struct { float w[256]; float red[256]; C pD[4][64]; } d;
  } u;
  __shared__ C Mh[16][4];
  __shared__ C vq[16][2];
  __shared__ C c7s[2];
  __shared__ float th[48];
  __shared__ float zz0s[15];

  // ---------- Phase B prep: angles, gates, product-state LUT (per block, redundant per batch) ----------
  if (tid < 15) zz0s[tid] = zz0[tid];
  if (tid < 192){
    int o = tid>>2, part = tid&3;
    int g = o/12, j = o - g*12;
    const float* f = (g==0) ? (slf + (size_t)b*128) : (nbr + ((size_t)b*3 + (g-1))*128);
    const float* wrow = Wp + j*128;
    const float4* f4 = (const float4*)(f + part*32);
    const float4* w4 = (const float4*)(wrow + part*32);
    float acc = 0.f;
    #pragma unroll
    for (int d=0; d<8; d++){
      float4 a = f4[d], c = w4[d];
      acc += a.x*c.x + a.y*c.y + a.z*c.z + a.w*c.w;
    }
    u.thp[o][part] = acc;
  }
  __syncthreads();
  if (tid < 48){
    int j = tid % 12;
    th[tid] = u.thp[tid][0] + u.thp[tid][1] + u.thp[tid][2] + u.thp[tid][3] + bp[j];
  }
  if (tid >= 64 && tid < 80){
    int q = tid - 64;
    C M[4]; fused_M(rot0[q*3+0], rot0[q*3+1], rot0[q*3+2], M);
    Mh[q][0]=M[0]; Mh[q][1]=M[1]; Mh[q][2]=M[2]; Mh[q][3]=M[3];
  }
  if (tid == 80){
    float t7 = zz0[7];
    float s,c; sincosf(0.5f*t7,&s,&c);
    c7s[0] = C{c,-s}; c7s[1] = C{c, s};
  }
  __syncthreads();
  if (tid < 16){
    C M[4]; fused_M(th[tid*3+0], th[tid*3+1], th[tid*3+2], M);
    vq[tid][0] = M[0]; vq[tid][1] = M[1];   // row 0 of e0^T * RxRyRz
  }
  __syncthreads();
  {
    int h = tid;
    C p = vq[0][(h>>7)&1];
    #pragma unroll
    for (int q=1;q<8;q++) p = cmul(p, vq[q][(h>>(7-q))&1]);
    float A = 0.f;
    #pragma unroll
    for (int kk=0;kk<7;kk++){
      int b0=(h>>(7-kk))&1, b1=(h>>(6-kk))&1;
      A += (b0==b1) ? zz0s[kk] : -zz0s[kk];
    }
    float s,c; sincosf(0.5f*A,&s,&c);
    u.lut.Vh[h] = cmul(p, C{c,-s});
    C pl = vq[8][(h>>7)&1];
    #pragma unroll
    for (int q=9;q<16;q++) pl = cmul(pl, vq[q][(h>>(15-q))&1]);
    float Al = 0.f;
    #pragma unroll
    for (int kk=8;kk<15;kk++){
      int b0=(h>>(15-kk))&1, b1=(h>>(14-kk))&1;
      Al += (b0==b1) ? zz0s[kk] : -zz0s[kk];
    }
    sincosf(0.5f*Al,&s,&c);
    u.lut.Vl[h] = cmul(pl, C{c,-s});
  }
  __syncthreads();

  // ---------- Phase B: psi0 tile + gates on qubits 4..15 (LDS bits 0..11) ----------
  #pragma unroll
  for (int it=0; it<16; ++it){
    int a = it*256 + tid;
    int i = (T<<12) | a;
    C amp = cmul(cmul(u.lut.Vh[i>>8], u.lut.Vl[i&255]), c7s[((i>>8)^(i>>7))&1]);
    big.S[SW(a)] = amp;
  }
  __syncthreads();
  pass3(big.S,tid, 0,1,2,   Mh[15],Mh[14],Mh[13], 4096); __syncthreads();
  pass3(big.S,tid, 3,4,5,   Mh[12],Mh[11],Mh[10], 4096); __syncthreads();
  pass3(big.S,tid, 6,7,8,   Mh[9], Mh[8], Mh[7],  4096); __syncthreads();
  pass3(big.S,tid, 9,10,11, Mh[6], Mh[5], Mh[4],  4096); __syncthreads();
  #pragma unroll
  for (int it=0; it<16; ++it){
    int a = it*256 + tid;
    g_buf1[b][(T<<12)|a] = big.S[SW(a)];
  }
  __threadfence();
  grid.sync();

  // ---------- Phase C: re-tile, gates on qubits 0..3, transpose to (t,k), prob partials ----------
  #pragma unroll
  for (int it=0; it<16; ++it){
    int a = it*256 + tid;
    big.S[SW(a)] = g_buf1[b][(it<<12)|(T<<8)|tid];
  }
  __syncthreads();
  pass3(big.S,tid, 8,9,10, Mh[3],Mh[2],Mh[1], 4096); __syncthreads();
  // final pass: qubit 0 (LDS bit 11), all 16 amps per thread into registers
  C Ar[8], Br[8];
  #pragma unroll
  for (int j=0;j<8;j++){
    int x = tid*8 + j;
    Ar[j] = big.S[SW(x)];
    Br[j] = big.S[SW(x|2048)];
    bfly(Ar[j], Br[j], Mh[0]);
  }
  __syncthreads();   // all reads complete -> safe to write permuted layout
  float pr[4] = {0.f,0.f,0.f,0.f};
  #pragma unroll
  for (int j=0;j<8;j++){
    int x = tid*8 + j;
    // a-coords: bit0=t0 bit1=k0 bit2=t1 bit3=k1 bit4=t2 bit5=k2 bit6=t3 bit7=k3
    //           bit8=t6 bit9=k6 bit10=t7 (bit11=k7 -> Ar/Br)
    int t03 = (x&1) | (((x>>2)&1)<<1) | (((x>>4)&1)<<2) | (((x>>6)&1)<<3);
    int k03 = ((x>>1)&1) | (((x>>3)&1)<<1) | (((x>>5)&1)<<2) | (((x>>7)&1)<<3);
    int t67 = ((x>>8)&1) | (((x>>10)&1)<<1);
    int k6  = (x>>9)&1;
    int tp  = t03 | (t67<<4);
    int klA = k03 | (k6<<4);
    big.S[SW2((tp<<6)|klA)]    = Ar[j];
    big.S[SW2((tp<<6)|klA|32)] = Br[j];
    pr[(j&1)|(((j>>2)&1)<<1)] += Ar[j].x*Ar[j].x + Ar[j].y*Ar[j].y
                               + Br[j].x*Br[j].x + Br[j].y*Br[j].y;
  }
  {
    int cIdx  = (tid&1) | (((tid>>2)&1)<<1) | (((tid>>4)&1)<<2) | (((tid>>6)&1)<<3);
    int gBits = (((tid>>1)&1)<<2) | (((tid>>3)&1)<<3) | (((tid>>5)&1)<<4) | (((tid>>7)&1)<<5);
    #pragma unroll
    for (int pi=0; pi<4; ++pi) u.pbuf[gBits|pi][cIdx] = pr[pi];
  }
  __syncthreads();
  if (tid < 64){
    float s = 0.f;
    #pragma unroll
    for (int c2=0;c2<16;c2++) s += u.pbuf[tid][c2];
    g_ppart[b][T][tid] = s;
  }
  __threadfence();
  grid.sync();

  // ---------- Phase D: per-batch pooling weights, weighted partial sums from LDS tile ----------
  {
    int t = tid;
    int t4=(t>>4)&1, t5=(t>>5)&1;
    int bin=(t&15)|(((t>>6)&1)<<4)|(((t>>7)&1)<<5);
    float wr=0.f;
    #pragma unroll
    for (int k5=0;k5<2;k5++)
      #pragma unroll
      for (int k4=0;k4<2;k4++)
        wr += g_ppart[b][t4|(k4<<1)|(t5<<2)|(k5<<3)][bin];
    u.d.red[tid] = wr;
    u.d.w[tid]   = wr;
  }
  __syncthreads();
  for (int s=128; s>0; s>>=1){ if (tid<s) u.d.red[tid]+=u.d.red[tid+s]; __syncthreads(); }
  float tot = u.d.red[0];
  __syncthreads();
  u.d.w[tid] = sqrtf(u.d.w[tid]/(tot + 1e-10f));
  __syncthreads();
  {
    int tq = tid>>6, kl = tid&63;
    int t4 = T&1, t5 = (T>>2)&1;
    C acc{0.f,0.f};
    #pragma unroll
    for (int s2=0;s2<16;s2++){
      int tp = tq*16+s2;
      int tfull = (tp&15) | (t4<<4) | (t5<<5) | ((tp>>4)<<6);
      C v = big.S[SW2((tp<<6)|kl)];
      float ww = u.d.w[tfull];
      acc.x += v.x*ww; acc.y += v.y*ww;
    }
    u.d.pD[tq][kl] = acc;
  }
  __syncthreads();
  if (tid < 64){
    C s{0.f,0.f};
    #pragma unroll
    for (int q=0;q<4;q++){ s.x += u.d.pD[q][tid].x; s.y += u.d.pD[q][tid].y; }
    g_s1p[b][T][tid] = s;
  }
  __threadfence();
  grid.sync();

  // ---------- Phase E: tail on 64 blocks (256-amp state) ----------
  if (blk < NB){
    const int be = blk;
    if (tid < 8){
      C M[4]; fused_M(rot1[tid*3+0], rot1[tid*3+1], rot1[tid*3+2], M);
      big.e.M1s[tid][0]=M[0]; big.e.M1s[tid][1]=M[1]; big.e.M1s[tid][2]=M[2]; big.e.M1s[tid][3]=M[3];
    }
    if (tid >= 8 && tid < 15) big.e.zz1s[tid-8] = zz1[tid-8];
    // gather s1[k] from 4 partials
    int k = tid;
    int kl = (k&15) | ((k>>6)<<4);
    int k4=(k>>4)&1, k5=(k>>5)&1;
    C s1{0.f,0.f};
    #pragma unroll
    for (int t5=0;t5<2;t5++)
      #pragma unroll
      for (int t4=0;t4<2;t4++){
        C v = g_s1p[be][t4|(k4<<1)|(t5<<2)|(k5<<3)][kl];
        s1.x += v.x; s1.y += v.y;
      }
    big.e.redE[tid] = s1.x*s1.x + s1.y*s1.y;
    __syncthreads();
    for (int s=128; s>0; s>>=1){ if (tid<s) big.e.redE[tid]+=big.e.redE[tid+s]; __syncthreads(); }
    float n1 = sqrtf(big.e.redE[0] + 1e-10f);
    s1.x /= n1; s1.y /= n1;
    // conv1 ZZ diagonal
    float A = 0.f;
    #pragma unroll
    for (int kk=0;kk<7;kk++){
      int b0=(tid>>(7-kk))&1, b1=(tid>>(6-kk))&1;
      A += (b0==b1) ? big.e.zz1s[kk] : -big.e.zz1s[kk];
    }
    float sa,ca; sincosf(0.5f*A,&sa,&ca);
    big.e.s8[tid] = cmul(s1, C{ca,-sa});
    __syncthreads();
    for (int q=0;q<8;q++){
      int p = 7-q, m = 1<<p;
      if ((tid & m) == 0){
        C x0=big.e.s8[tid], x1=big.e.s8[tid|m];
        bfly(x0,x1,&big.e.M1s[q][0]);
        big.e.s8[tid]=x0; big.e.s8[tid|m]=x1;
      }
      __syncthreads();
    }
    if (tid < 16){
      float s = 0.f;
      #pragma unroll
      for (int k2=0;k2<16;k2++){ C v=big.e.s8[expand44(tid,k2)]; s += v.x*v.x + v.y*v.y; }
      big.e.p2[tid] = s;
    }
    __syncthreads();
    if (tid == 0){ float S2=0.f; for (int i2=0;i2<16;i2++) S2+=big.e.p2[i2]; big.e.sc[0]=S2; }
    __syncthreads();
    if (tid < 16) big.e.p2[tid] = sqrtf(big.e.p2[tid]/(big.e.sc[0]+1e-10f));
    __syncthreads();
    if (tid < 16){
      C a2 = C{0.f,0.f};
      #pragma unroll
      for (int t2=0;t2<16;t2++){ C v=big.e.s8[expand44(t2,tid)]; float ww=big.e.p2[t2]; a2.x+=v.x*ww; a2.y+=v.y*ww; }
      big.e.s2[tid] = a2;
    }
    __syncthreads();
    if (tid == 0){
      float nn=0.f; for (int i2=0;i2<16;i2++) nn += big.e.s2[i2].x*big.e.s2[i2].x + big.e.s2[i2].y*big.e.s2[i2].y;
      big.e.sc[1] = nn + 1e-10f;
    }
    __syncthreads();
    if (tid < 4){
      float z = 0.f;
      #pragma unroll
      for (int idx=0; idx<16; idx++){
        C v = big.e.s2[idx];
        float prb = (v.x*v.x + v.y*v.y)/big.e.sc[1];
        z += ((idx>>(3-tid))&1) ? -prb : prb;
      }
      big.e.zm[tid] = z;
    }
    __syncthreads();
    if (tid < 64){
      float r = bo[tid];
      #pragma unroll
      for (int q=0;q<4;q++) r += big.e.zm[q]*Wo[tid*4+q];
      out[(size_t)be*64 + tid] = r;
    }
  }
}

// ================= FALLBACK PATH (verified 4-kernel pipeline) =================
__global__ __launch_bounds__(256) void k_prep(const float* __restrict__ nbr,
    const float* __restrict__ slf, const float* __restrict__ Wp,
    const float* __restrict__ bp, const float* __restrict__ rot0,
    const float* __restrict__ zz0, const float* __restrict__ rot1){
  int b = blockIdx.x, tid = threadIdx.x;
  __shared__ float th[48];
  __shared__ C vq[16][2];
  __shared__ float zz0s[15];
  if (tid < 15) zz0s[tid] = zz0[tid];
  if (tid < 48){
    int q = tid/3, c = tid - q*3, g = q>>2, j = (q&3)*3 + c;
    const float* f = (g==0) ? (slf + (size_t)b*128) : (nbr + ((size_t)b*3 + (g-1))*128);
    const float* wrow = Wp + j*128;
    float acc = bp[j];
    for (int d=0; d<128; d++) acc += f[d]*wrow[d];
    th[tid] = acc;
  }
  __syncthreads();
  if (tid < 16){
    C M[4];
    fused_M(th[tid*3+0], th[tid*3+1], th[tid*3+2], M);
    vq[tid][0] = M[0]; vq[tid][1] = M[1];
  }
  __syncthreads();
  {
    int h = tid;
    C p = vq[0][(h>>7)&1];
    #pragma unroll
    for (int q=1;q<8;q++) p = cmul(p, vq[q][(h>>(7-q))&1]);
    float A = 0.f;
    #pragma unroll
    for (int kk=0;kk<7;kk++){
      int b0=(h>>(7-kk))&1, b1=(h>>(6-kk))&1;
      A += (b0==b1) ? zz0s[kk] : -zz0s[kk];
    }
    float s,c; sincosf(0.5f*A,&s,&c);
    g_lut[b][h] = cmul(p, C{c,-s});
    C pl = vq[8][(h>>7)&1];
    #pragma unroll
    for (int q=9;q<16;q++) pl = cmul(pl, vq[q][(h>>(15-q))&1]);
    float Al = 0.f;
    #pragma unroll
    for (int kk=8;kk<15;kk++){
      int b0=(h>>(15-kk))&1, b1=(h>>(14-kk))&1;
      Al += (b0==b1) ? zz0s[kk] : -zz0s[kk];
    }
    sincosf(0.5f*Al,&s,&c);
    g_lut[b][256+h] = cmul(pl, C{c,-s});
  }
  if (b == 0){
    if (tid < 16){
      fused_M(rot0[tid*3+0], rot0[tid*3+1], rot0[tid*3+2], &g_M0[tid][0]);
    } else if (tid < 24){
      int q = tid-16;
      fused_M(rot1[q*3+0], rot1[q*3+1], rot1[q*3+2], &g_M1[q][0]);
    } else if (tid == 24){
      float t7 = zz0[7];
      float s,c; sincosf(0.5f*t7,&s,&c);
      g_c7[0] = C{c,-s};
      g_c7[1] = C{c, s};
    }
  }
}

__global__ __launch_bounds__(256) void k_conv0_a(){
  int blk = blockIdx.x, b = blk>>4, T = blk&15, tid = threadIdx.x;
  __shared__ C S[4096];
  __shared__ C Vh[256], Vl[256];
  __shared__ C Mg[12][4];
  __shared__ C c7sh[2];
  Vh[tid] = g_lut[b][tid];
  Vl[tid] = g_lut[b][256+tid];
  if (tid < 48) Mg[tid>>2][tid&3] = g_M0[4+(tid>>2)][tid&3];
  if (tid < 2)  c7sh[tid] = g_c7[tid];
  __syncthreads();
  #pragma unroll
  for (int it=0; it<16; ++it){
    int a = it*256 + tid;
    int i = (T<<12) | a;
    C amp = cmul(cmul(Vh[i>>8], Vl[i&255]), c7sh[((i>>8)^(i>>7))&1]);
    S[SW(a)] = amp;
  }
  __syncthreads();
  pass3(S,tid, 0,1,2,  Mg[11],Mg[10],Mg[9], 4096); __syncthreads();
  pass3(S,tid, 3,4,5,  Mg[8], Mg[7], Mg[6], 4096); __syncthreads();
  pass3(S,tid, 6,7,8,  Mg[5], Mg[4], Mg[3], 4096); __syncthreads();
  pass3(S,tid, 9,10,11,Mg[2], Mg[1], Mg[0], 4096); __syncthreads();
  #pragma unroll
  for (int it=0; it<16; ++it){
    int a = it*256 + tid;
    g_buf1[b][(T<<12)|a] = S[SW(a)];
  }
}

__global__ __launch_bounds__(256) void k_conv0_b(){
  int blk = blockIdx.x, b = blk>>4, T2 = blk&15, tid = threadIdx.x;
  __shared__ C S[4096];
  __shared__ C Mhh[4][4];
  __shared__ float pbuf[4][256];
  if (tid < 16) Mhh[tid>>2][tid&3] = g_M0[tid>>2][tid&3];
  #pragma unroll
  for (int it=0; it<16; ++it){
    int a = it*256 + tid;
    int i = (it<<12) | (T2<<8) | tid;
    S[SW(a)] = g_buf1[b][i];
  }
  __syncthreads();
  pass3(S,tid, 8,9,10, Mhh[3],Mhh[2],Mhh[1], 4096); __syncthreads();
  pass1(S,tid, 11, Mhh[0], 4096); __syncthreads();
  float pr0=0.f, pr1=0.f, pr2=0.f, pr3=0.f;
  #pragma unroll
  for (int it=0; it<16; ++it){
    int a = it*256 + tid;
    int i = (it<<12) | (T2<<8) | tid;
    C v = S[SW(a)];
    unsigned t = ceven((unsigned)i), k = ceven((unsigned)i>>1);
    g_buf2[b][(t<<8)|k] = v;
    float pw = v.x*v.x + v.y*v.y;
    int slot = (it&1) | (((it>>2)&1)<<1);
    if      (slot==0) pr0 += pw;
    else if (slot==1) pr1 += pw;
    else if (slot==2) pr2 += pw;
    else              pr3 += pw;
  }
  pbuf[0][tid]=pr0; pbuf[1][tid]=pr1; pbuf[2][tid]=pr2; pbuf[3][tid]=pr3;
  __syncthreads();
  if (tid < 64){
    int t03 = tid & 15, s = tid>>4;
    float sum = 0.f;
    #pragma unroll
    for (int j=0;j<16;j++){
      int tp = (t03&1) | ((j&1)<<1) | (((t03>>1)&1)<<2) | (((j>>1)&1)<<3)
             | (((t03>>2)&1)<<4) | (((j>>2)&1)<<5) | (((t03>>3)&1)<<6) | (((j>>3)&1)<<7);
      sum += pbuf[s][tp];
    }
    g_ppart[b][T2][tid] = sum;
  }
}

__global__ __launch_bounds__(256) void k_tail(const float* __restrict__ zz1,
    const float* __restrict__ Wo, const float* __restrict__ bo,
    float* __restrict__ out){
  int b = blockIdx.x, tid = threadIdx.x;
  __shared__ float w[256], red[256];
  __shared__ C M1s[8][4];
  __shared__ float zz1s[7];
  __shared__ C s8[256];
  __shared__ float p2[16];
  __shared__ C s2[16];
  __shared__ float sc[2];
  __shared__ float zm[4];
  if (tid < 32) M1s[tid>>2][tid&3] = g_M1[tid>>2][tid&3];
  if (tid < 7)  zz1s[tid] = zz1[tid];
  {
    int t4=(tid>>4)&1, t5=(tid>>5)&1, t6=(tid>>6)&1, t7=(tid>>7)&1;
    int bin = (tid&15) | (t6<<4) | (t7<<5);
    float wr = 0.f;
    #pragma unroll
    for (int k5=0;k5<2;k5++)
      #pragma unroll
      for (int k4=0;k4<2;k4++)
        wr += g_ppart[b][t4 | (k4<<1) | (t5<<2) | (k5<<3)][bin];
    red[tid] = wr;
    w[tid] = wr;
  }
  __syncthreads();
  for (int s=128; s>0; s>>=1){ if (tid<s) red[tid]+=red[tid+s]; __syncthreads(); }
  float tot = red[0];
  __syncthreads();
  w[tid] = sqrtf(w[tid]/(tot + 1e-10f));
  __syncthreads();
  C acc = C{0.f,0.f};
  #pragma unroll 4
  for (int tt=0; tt<256; ++tt){
    C v = g_buf2[b][(tt<<8)|tid];
    float ww = w[tt];
    acc.x += v.x*ww; acc.y += v.y*ww;
  }
  red[tid] = acc.x*acc.x + acc.y*acc.y;
  __syncthreads();
  for (int s=128; s>0; s>>=1){ if (tid<s) red[tid]+=red[tid+s]; __syncthreads(); }
  float n1 = sqrtf(red[0] + 1e-10f);
  C s1 = C{acc.x/n1, acc.y/n1};
  float A = 0.f;
  #pragma unroll
  for (int kk=0;kk<7;kk++){
    int b0=(tid>>(7-kk))&1, b1=(tid>>(6-kk))&1;
    A += (b0==b1) ? zz1s[kk] : -zz1s[kk];
  }
  float sa,ca; sincosf(0.5f*A,&sa,&ca);
  s8[tid] = cmul(s1, C{ca,-sa});
  __syncthreads();
  for (int q=0;q<8;q++){
    int p = 7-q, m = 1<<p;
    if ((tid & m) == 0){
      C x0=s8[tid], x1=s8[tid|m];
      bfly(x0,x1,&M1s[q][0]);
      s8[tid]=x0; s8[tid|m]=x1;
    }
    __syncthreads();
  }
  if (tid < 16){
    float s = 0.f;
    #pragma unroll
    for (int k2=0;k2<16;k2++){ C v=s8[expand44(tid,k2)]; s += v.x*v.x + v.y*v.y; }
    p2[tid] = s;
  }
  __syncthreads();
  if (tid == 0){ float S2=0.f; for (int i2=0;i2<16;i2++) S2+=p2[i2]; sc[0]=S2; }
  __syncthreads();
  if (tid < 16) p2[tid] = sqrtf(p2[tid]/(sc[0]+1e-10f));
  __syncthreads();
  if (tid < 16){
    C a2 = C{0.f,0.f};
    #pragma unroll
    for (int t2=0;t2<16;t2++){ C v=s8[expand44(t2,tid)]; float ww=p2[t2]; a2.x+=v.x*ww; a2.y+=v.y*ww; }
    s2[tid] = a2;
  }
  __syncthreads();
  if (tid == 0){
    float nn=0.f; for (int i2=0;i2<16;i2++) nn += s2[i2].x*s2[i2].x + s2[i2].y*s2[i2].y;
    sc[1] = nn + 1e-10f;
  }
  __syncthreads();
  if (tid < 4){
    float z = 0.f;
    #pragma unroll
    for (int idx=0; idx<16; idx++){
      C v = s2[idx];
      float pr = (v.x*v.x + v.y*v.y)/sc[1];
      z += ((idx>>(3-tid))&1) ? -pr : pr;
    }
    zm[tid] = z;
  }
  __syncthreads();
  if (tid < 64){
    float r = bo[tid];
    #pragma unroll
    for (int q=0;q<4;q++) r += zm[q]*Wo[tid*4+q];
    out[(size_t)b*64 + tid] = r;
  }
}

extern "C" void kernel_launch(void* const* d_in, const int* in_sizes, int n_in,
                              void* d_out, int out_size, void* d_ws, size_t ws_size,
                              hipStream_t stream) {
  const float* nbr  = (const float*)d_in[0];
  const float* slf  = (const float*)d_in[1];
  const float* Wp   = (const float*)d_in[2];
  const float* bp   = (const float*)d_in[3];
  const float* rot0 = (const float*)d_in[4];
  const float* zz0  = (const float*)d_in[5];
  const float* rot1 = (const float*)d_in[6];
  const float* zz1  = (const float*)d_in[7];
  const float* Wo   = (const float*)d_in[8];
  const float* bo   = (const float*)d_in[9];
  float* out = (float*)d_out;

  // Deterministic host-side check: can the cooperative grid (1024 blocks) be co-resident?
  int dev = 0; (void)hipGetDevice(&dev);
  int nCU = 0; (void)hipDeviceGetAttribute(&nCU, hipDeviceAttributeMultiprocessorCount, dev);
  int maxBlk = 0;
  hipError_t occErr = hipOccupancyMaxActiveBlocksPerMultiprocessor(&maxBlk, (const void*)k_fused, 256, 0);
  bool useCoop = (occErr == hipSuccess) && ((long)maxBlk * (long)nCU >= 1024L);

  if (useCoop) {
    void* args[] = {(void*)&nbr,(void*)&slf,(void*)&Wp,(void*)&bp,(void*)&rot0,
                    (void*)&zz0,(void*)&rot1,(void*)&zz1,(void*)&Wo,(void*)&bo,(void*)&out};
    hipError_t e = hipLaunchCooperativeKernel((void*)k_fused, dim3(1024), dim3(256), args, 0, stream);
    if (e == hipSuccess) return;
    (void)hipGetLastError(); // clear; fall through to the verified pipeline
  }

  hipLaunchKernelGGL(k_prep,    dim3(NB),   dim3(256), 0, stream, nbr, slf, Wp, bp, rot0, zz0, rot1);
  hipLaunchKernelGGL(k_conv0_a, dim3(NB*16),dim3(256), 0, stream);
  hipLaunchKernelGGL(k_conv0_b, dim3(NB*16),dim3(256), 0, stream);
  hipLaunchKernelGGL(k_tail,    dim3(NB),   dim3(256), 0, stream, zz1, Wo, bo, out);
}

// Round 3
// 20.180 us; speedup vs baseline: 3.9547x; 3.9298x over previous
//
#include <hip/hip_runtime.h>
#include <math.h>

#define NB 64

struct C { float x, y; };

__device__ __forceinline__ C cmul(C a, C b){ return C{a.x*b.x - a.y*b.y, a.x*b.y + a.y*b.x}; }

// new_j = sum_i x_i * G[i][j]  (reference einsum contracts gate's FIRST index with state)
__device__ __forceinline__ void bfly(C& x0, C& x1, const C* G){
  C n0 = C{x0.x*G[0].x - x0.y*G[0].y + x1.x*G[2].x - x1.y*G[2].y,
           x0.x*G[0].y + x0.y*G[0].x + x1.x*G[2].y + x1.y*G[2].x};
  C n1 = C{x0.x*G[1].x - x0.y*G[1].y + x1.x*G[3].x - x1.y*G[3].y,
           x0.x*G[1].y + x0.y*G[1].x + x1.x*G[3].y + x1.y*G[3].x};
  x0 = n0; x1 = n1;
}

// interleave: t2 bits -> even positions, k2 bits -> odd positions
__device__ __forceinline__ int expand44(int t2, int k2){
  int j=0;
  #pragma unroll
  for (int m=0;m<4;m++){ j |= ((t2>>m)&1)<<(2*m); j |= ((k2>>m)&1)<<(2*m+1); }
  return j;
}

// M = Rx(tx)*Ry(ty)*Rz(tz), row-major M[i*2+j]; reference applies new = x^T * M
__device__ void fused_M(float tx, float ty, float tz, C* M){
  float cx=cosf(0.5f*tx), sx=sinf(0.5f*tx);
  float cy=cosf(0.5f*ty), sy=sinf(0.5f*ty);
  float cz=cosf(0.5f*tz), sz=sinf(0.5f*tz);
  C b0 = C{ cx*cy, -sx*sy};
  C b1 = C{-cx*sy, -sx*cy};
  C b2 = C{ cx*sy, -sx*cy};
  C b3 = C{ cx*cy,  sx*sy};
  C e0 = C{cz,-sz}, e1 = C{cz, sz};
  M[0]=cmul(b0,e0); M[1]=cmul(b1,e1);
  M[2]=cmul(b2,e0); M[3]=cmul(b3,e1);
}

// ================= SINGLE KERNEL: rank-2 factored simulation =================
// psi'(h,l) = sum_{r=0,1} A_r(h) * B_r(l)  after conv0 (boundary ZZ pair is rank-2).
// Pooling probs/weighted sums via 16-entry Gram vectors + 16^3 contractions.
__global__ __launch_bounds__(256) void k_all(
    const float* __restrict__ nbr, const float* __restrict__ slf,
    const float* __restrict__ Wp, const float* __restrict__ bp,
    const float* __restrict__ rot0, const float* __restrict__ zz0,
    const float* __restrict__ rot1, const float* __restrict__ zz1,
    const float* __restrict__ Wo, const float* __restrict__ bo,
    float* __restrict__ out)
{
  const int b = blockIdx.x, tid = threadIdx.x;

  __shared__ float thp[48][4];
  __shared__ float th[48];
  __shared__ C vq[16][2];
  __shared__ float zz0s[15];
  __shared__ C M0s[16][4];
  __shared__ C lam[2];
  __shared__ C W[4][256];               // A0, A1, B0, B1 (256-amp byte-functions)
  __shared__ float GH00[16], GH11[16];
  __shared__ float GL00[16], GL11[16];
  __shared__ C GH01[16], GL01[16];
  __shared__ float w[256], red[256];
  __shared__ C Mx[2][16][16];
  // tail
  __shared__ C s8[256];
  __shared__ C M1s[8][4];
  __shared__ float zz1s[7];
  __shared__ float p2[16];
  __shared__ C s2[16];
  __shared__ float sc[2];
  __shared__ float zm[4];

  // ---------- angles (verified in fused phase-B) ----------
  if (tid < 15) zz0s[tid] = zz0[tid];
  if (tid < 192){
    int o = tid>>2, part = tid&3;
    int g = o/12, j = o - g*12;
    const float* f = (g==0) ? (slf + (size_t)b*128) : (nbr + ((size_t)b*3 + (g-1))*128);
    const float4* f4 = (const float4*)(f + part*32);
    const float4* w4 = (const float4*)(Wp + j*128 + part*32);
    float acc = 0.f;
    #pragma unroll
    for (int d=0; d<8; d++){
      float4 a = f4[d], c = w4[d];
      acc += a.x*c.x + a.y*c.y + a.z*c.z + a.w*c.w;
    }
    thp[o][part] = acc;
  }
  __syncthreads();
  if (tid < 48) th[tid] = thp[tid][0]+thp[tid][1]+thp[tid][2]+thp[tid][3] + bp[tid%12];
  if (tid >= 64 && tid < 80){
    int q = tid-64;
    fused_M(rot0[q*3+0], rot0[q*3+1], rot0[q*3+2], &M0s[q][0]);
  }
  if (tid == 80){
    // boundary ZZ pair rank-2 split: [[a,b],[b,a]] = c*(1x1) + (-i s)*(sgn x sgn)
    float s,c; sincosf(0.5f*zz0[7],&s,&c);
    lam[0] = C{c,0.f}; lam[1] = C{0.f,-s};
  }
  __syncthreads();
  if (tid < 16){
    C M[4]; fused_M(th[tid*3+0], th[tid*3+1], th[tid*3+2], M);
    vq[tid][0] = M[0]; vq[tid][1] = M[1];   // row 0 of e0^T * RxRyRz (encoding on |0>)
  }
  __syncthreads();

  // ---------- byte-function init: Vh/Vl (verified) -> A0,A1,B0,B1 ----------
  {
    int h = tid;
    C p = vq[0][(h>>7)&1];
    #pragma unroll
    for (int q=1;q<8;q++) p = cmul(p, vq[q][(h>>(7-q))&1]);
    float A = 0.f;
    #pragma unroll
    for (int kk=0;kk<7;kk++){
      int b0=(h>>(7-kk))&1, b1=(h>>(6-kk))&1;
      A += (b0==b1) ? zz0s[kk] : -zz0s[kk];
    }
    float s,c; sincosf(0.5f*A,&s,&c);
    C Vh = cmul(p, C{c,-s});
    C pl = vq[8][(h>>7)&1];
    #pragma unroll
    for (int q=9;q<16;q++) pl = cmul(pl, vq[q][(h>>(15-q))&1]);
    float Al = 0.f;
    #pragma unroll
    for (int kk=8;kk<15;kk++){
      int b0=(h>>(15-kk))&1, b1=(h>>(14-kk))&1;
      Al += (b0==b1) ? zz0s[kk] : -zz0s[kk];
    }
    sincosf(0.5f*Al,&s,&c);
    C Vl = cmul(pl, C{c,-s});
    // A_r(h) = Vh(h) * lam_r * sgn_r(b7),  b7 = h bit0
    W[0][h] = cmul(Vh, lam[0]);
    C a1 = cmul(Vh, lam[1]);
    if (h & 1){ a1.x = -a1.x; a1.y = -a1.y; }
    W[1][h] = a1;
    // B_r(l) = Vl(l) * sgn_r(b8),  b8 = l bit7
    W[2][h] = Vl;
    W[3][h] = ((h>>7)&1) ? C{-Vl.x,-Vl.y} : Vl;
  }
  __syncthreads();

  // ---------- conv0 rotations: 8 butterfly levels on each 256-vector ----------
  // h bit pb <-> qubit 7-pb (matrix M0s[7-pb]); l bit pb <-> qubit 15-pb (M0s[15-pb])
  for (int pb=0; pb<8; ++pb){
    int arr = tid>>6, pi = tid&63;
    const C* G = (arr<2) ? &M0s[7-pb][0] : &M0s[15-pb][0];
    int m = 1<<pb;
    #pragma unroll
    for (int rep=0; rep<2; ++rep){
      int p = pi + rep*64;
      int x = ((p>>pb)<<(pb+1)) | (p & (m-1));
      C x0 = W[arr][x], x1 = W[arr][x|m];
      bfly(x0,x1,G);
      W[arr][x]=x0; W[arr][x|m]=x1;
    }
    __syncthreads();
  }

  // ---------- Gram vectors: GH_{rr'}(tH) = sum_kH A_r conj(A_r'), same for GL ----------
  if (tid < 32){
    int side = tid>>4, tq = tid&15;
    float g00=0.f, g11=0.f; C g01{0.f,0.f};
    #pragma unroll
    for (int kq=0;kq<16;kq++){
      int idx = expand44(tq,kq);
      C a0 = W[side*2+0][idx], a1 = W[side*2+1][idx];
      g00 += a0.x*a0.x + a0.y*a0.y;
      g11 += a1.x*a1.x + a1.y*a1.y;
      g01.x += a0.x*a1.x + a0.y*a1.y;   // a0 * conj(a1)
      g01.y += a0.y*a1.x - a0.x*a1.y;
    }
    if (side==0){ GH00[tq]=g00; GH11[tq]=g11; GH01[tq]=g01; }
    else        { GL00[tq]=g00; GL11[tq]=g11; GL01[tq]=g01; }
  }
  __syncthreads();

  // ---------- p(t) = GH00*GL00 + GH11*GL11 + 2Re(GH01*GL01); weights ----------
  {
    int tH = tid>>4, tL = tid&15;
    C gh = GH01[tH], gl = GL01[tL];
    float p = GH00[tH]*GL00[tL] + GH11[tH]*GL11[tL]
            + 2.f*(gh.x*gl.x - gh.y*gl.y);
    p = fmaxf(p, 0.f);                   // guard fp cancellation before sqrt
    red[tid] = p; w[tid] = p;
  }
  __syncthreads();
  for (int s=128; s>0; s>>=1){ if (tid<s) red[tid]+=red[tid+s]; __syncthreads(); }
  float tot = red[0];
  __syncthreads();
  w[tid] = sqrtf(w[tid]/(tot + 1e-10f));
  __syncthreads();

  // ---------- Mx[r][tH][kL] = sum_tL w(tH,tL) * B_r(tL,kL) ----------
  #pragma unroll
  for (int rep=0; rep<2; ++rep){
    int e = tid + rep*256;
    int r = e>>8, tH = (e>>4)&15, kL = e&15;
    C acc{0.f,0.f};
    #pragma unroll
    for (int tL=0;tL<16;tL++){
      float ww = w[(tH<<4)|tL];
      C bv = W[2+r][expand44(tL,kL)];
      acc.x += ww*bv.x; acc.y += ww*bv.y;
    }
    Mx[r][tH][kL] = acc;
  }
  __syncthreads();

  // ---------- s1(k) = sum_r sum_tH A_r(tH,kH) * Mx[r][tH][kL] ----------
  C s1{0.f,0.f};
  {
    int kH = tid>>4, kL = tid&15;
    #pragma unroll
    for (int tH=0;tH<16;tH++){
      int ia = expand44(tH,kH);
      C a0 = W[0][ia], m0 = Mx[0][tH][kL];
      C a1 = W[1][ia], m1 = Mx[1][tH][kL];
      s1.x += a0.x*m0.x - a0.y*m0.y + a1.x*m1.x - a1.y*m1.y;
      s1.y += a0.x*m0.y + a0.y*m0.x + a1.x*m1.y + a1.y*m1.x;
    }
  }
  red[tid] = s1.x*s1.x + s1.y*s1.y;
  __syncthreads();
  for (int s=128; s>0; s>>=1){ if (tid<s) red[tid]+=red[tid+s]; __syncthreads(); }
  float n1 = sqrtf(red[0] + 1e-10f);
  s1.x /= n1; s1.y /= n1;

  // ---------- tail: conv1 + pool2 + measure + head (verified k_tail) ----------
  if (tid < 8) fused_M(rot1[tid*3+0], rot1[tid*3+1], rot1[tid*3+2], &M1s[tid][0]);
  if (tid >= 8 && tid < 15) zz1s[tid-8] = zz1[tid-8];
  __syncthreads();
  float A = 0.f;
  #pragma unroll
  for (int kk=0;kk<7;kk++){
    int b0=(tid>>(7-kk))&1, b1=(tid>>(6-kk))&1;
    A += (b0==b1) ? zz1s[kk] : -zz1s[kk];
  }
  float sa,ca; sincosf(0.5f*A,&sa,&ca);
  s8[tid] = cmul(s1, C{ca,-sa});
  __syncthreads();
  for (int q=0;q<8;q++){
    int p = 7-q, m = 1<<p;
    if ((tid & m) == 0){
      C x0=s8[tid], x1=s8[tid|m];
      bfly(x0,x1,&M1s[q][0]);
      s8[tid]=x0; s8[tid|m]=x1;
    }
    __syncthreads();
  }
  if (tid < 16){
    float s = 0.f;
    #pragma unroll
    for (int k2=0;k2<16;k2++){ C v=s8[expand44(tid,k2)]; s += v.x*v.x + v.y*v.y; }
    p2[tid] = s;
  }
  __syncthreads();
  if (tid == 0){ float S2=0.f; for (int i2=0;i2<16;i2++) S2+=p2[i2]; sc[0]=S2; }
  __syncthreads();
  if (tid < 16) p2[tid] = sqrtf(p2[tid]/(sc[0]+1e-10f));
  __syncthreads();
  if (tid < 16){
    C a2 = C{0.f,0.f};
    #pragma unroll
    for (int t2=0;t2<16;t2++){ C v=s8[expand44(t2,tid)]; float ww=p2[t2]; a2.x+=v.x*ww; a2.y+=v.y*ww; }
    s2[tid] = a2;
  }
  __syncthreads();
  if (tid == 0){
    float nn=0.f; for (int i2=0;i2<16;i2++) nn += s2[i2].x*s2[i2].x + s2[i2].y*s2[i2].y;
    sc[1] = nn + 1e-10f;
  }
  __syncthreads();
  if (tid < 4){
    float z = 0.f;
    #pragma unroll
    for (int idx=0; idx<16; idx++){
      C v = s2[idx];
      float pr = (v.x*v.x + v.y*v.y)/sc[1];
      z += ((idx>>(3-tid))&1) ? -pr : pr;
    }
    zm[tid] = z;
  }
  __syncthreads();
  if (tid < 64){
    float r = bo[tid];
    #pragma unroll
    for (int q=0;q<4;q++) r += zm[q]*Wo[tid*4+q];
    out[(size_t)b*64 + tid] = r;
  }
}

extern "C" void kernel_launch(void* const* d_in, const int* in_sizes, int n_in,
                              void* d_out, int out_size, void* d_ws, size_t ws_size,
                              hipStream_t stream) {
  const float* nbr  = (const float*)d_in[0];
  const float* slf  = (const float*)d_in[1];
  const float* Wp   = (const float*)d_in[2];
  const float* bp   = (const float*)d_in[3];
  const float* rot0 = (const float*)d_in[4];
  const float* zz0  = (const float*)d_in[5];
  const float* rot1 = (const float*)d_in[6];
  const float* zz1  = (const float*)d_in[7];
  const float* Wo   = (const float*)d_in[8];
  const float* bo   = (const float*)d_in[9];
  float* out = (float*)d_out;

  hipLaunchKernelGGL(k_all, dim3(NB), dim3(256), 0, stream,
                     nbr, slf, Wp, bp, rot0, zz0, rot1, zz1, Wo, bo, out);
}

// Round 4
// 17.569 us; speedup vs baseline: 4.5425x; 1.1486x over previous
//
#include <hip/hip_runtime.h>
#include <math.h>

#define NB 64

struct C { float x, y; };

__device__ __forceinline__ C cmul(C a, C b){ return C{a.x*b.x - a.y*b.y, a.x*b.y + a.y*b.x}; }

// new_j = sum_i x_i * G[i][j]  (reference einsum contracts gate's FIRST index with state)
__device__ __forceinline__ void bfly(C& x0, C& x1, const C* G){
  C n0 = C{x0.x*G[0].x - x0.y*G[0].y + x1.x*G[2].x - x1.y*G[2].y,
           x0.x*G[0].y + x0.y*G[0].x + x1.x*G[2].y + x1.y*G[2].x};
  C n1 = C{x0.x*G[1].x - x0.y*G[1].y + x1.x*G[3].x - x1.y*G[3].y,
           x0.x*G[1].y + x0.y*G[1].x + x1.x*G[3].y + x1.y*G[3].x};
  x0 = n0; x1 = n1;
}

// interleave: t2 bits -> even positions, k2 bits -> odd positions
__device__ __forceinline__ int expand44(int t2, int k2){
  int j=0;
  #pragma unroll
  for (int m=0;m<4;m++){ j |= ((t2>>m)&1)<<(2*m); j |= ((k2>>m)&1)<<(2*m+1); }
  return j;
}

// M = Rx(tx)*Ry(ty)*Rz(tz), row-major M[i*2+j]; reference applies new = x^T * M
__device__ void fused_M(float tx, float ty, float tz, C* M){
  float cx=cosf(0.5f*tx), sx=sinf(0.5f*tx);
  float cy=cosf(0.5f*ty), sy=sinf(0.5f*ty);
  float cz=cosf(0.5f*tz), sz=sinf(0.5f*tz);
  C b0 = C{ cx*cy, -sx*sy};
  C b1 = C{-cx*sy, -sx*cy};
  C b2 = C{ cx*sy, -sx*cy};
  C b3 = C{ cx*cy,  sx*sy};
  C e0 = C{cz,-sz}, e1 = C{cz, sz};
  M[0]=cmul(b0,e0); M[1]=cmul(b1,e1);
  M[2]=cmul(b2,e0); M[3]=cmul(b3,e1);
}

// ================= SINGLE KERNEL: rank-2 factored simulation, low-barrier =================
__global__ __launch_bounds__(256) void k_all(
    const float* __restrict__ nbr, const float* __restrict__ slf,
    const float* __restrict__ Wp, const float* __restrict__ bp,
    const float* __restrict__ rot0, const float* __restrict__ zz0,
    const float* __restrict__ rot1, const float* __restrict__ zz1,
    const float* __restrict__ Wo, const float* __restrict__ bo,
    float* __restrict__ out)
{
  const int b = blockIdx.x, tid = threadIdx.x;

  __shared__ float thp[48][4];
  __shared__ float th[48];
  __shared__ C vq[16][2];
  __shared__ float zz0s[15];
  __shared__ C M0s[16][4];
  __shared__ C lam[2];
  __shared__ C W[4][256];               // A0, A1, B0, B1
  __shared__ float GH00[16], GH11[16], GL00[16], GL11[16];
  __shared__ C GH01[16], GL01[16];
  __shared__ float w[256];
  __shared__ float part[4];
  __shared__ C Mx[2][16][16];
  __shared__ C s8[256];
  __shared__ C M1s[8][4];
  __shared__ float zz1s[7];

  // ---- prefetch head weights into registers (used only at the very end) ----
  float4 wo4 = make_float4(0.f,0.f,0.f,0.f); float bor = 0.f;
  if (tid < 64){ wo4 = ((const float4*)Wo)[tid]; bor = bo[tid]; }

  // ---- parallel prep: angle GEMM partials (tid<192) + gate matrices (tid>=192) ----
  if (tid < 15) zz0s[tid] = zz0[tid];
  if (tid < 192){
    int o = tid>>2, prt = tid&3;
    int g = o/12, j = o - g*12;
    const float* f = (g==0) ? (slf + (size_t)b*128) : (nbr + ((size_t)b*3 + (g-1))*128);
    const float4* f4 = (const float4*)(f + prt*32);
    const float4* w4 = (const float4*)(Wp + j*128 + prt*32);
    float acc = 0.f;
    #pragma unroll
    for (int d=0; d<8; d++){
      float4 a = f4[d], c = w4[d];
      acc += a.x*c.x + a.y*c.y + a.z*c.z + a.w*c.w;
    }
    thp[o][prt] = acc;
  } else if (tid < 208){
    int q = tid-192;
    fused_M(rot0[q*3+0], rot0[q*3+1], rot0[q*3+2], &M0s[q][0]);
  } else if (tid < 216){
    int q = tid-208;
    fused_M(rot1[q*3+0], rot1[q*3+1], rot1[q*3+2], &M1s[q][0]);
  } else if (tid < 223){
    zz1s[tid-216] = zz1[tid-216];
  } else if (tid == 223){
    // boundary ZZ pair rank-2 split: [[a,b],[b,a]] = c*(1x1) + (-i s)*(sgn x sgn)
    float s,c; sincosf(0.5f*zz0[7],&s,&c);
    lam[0] = C{c,0.f}; lam[1] = C{0.f,-s};
  }
  __syncthreads();                                        // B1
  if (tid < 48) th[tid] = thp[tid][0]+thp[tid][1]+thp[tid][2]+thp[tid][3] + bp[tid%12];
  __syncthreads();                                        // B2
  if (tid < 16){
    C M[4]; fused_M(th[tid*3+0], th[tid*3+1], th[tid*3+2], M);
    vq[tid][0] = M[0]; vq[tid][1] = M[1];   // row 0 of e0^T * RxRyRz (encoding on |0>)
  }
  __syncthreads();                                        // B3

  // ---- byte-function init: Vh/Vl -> A0,A1,B0,B1 (verified) ----
  {
    int h = tid;
    C p = vq[0][(h>>7)&1];
    #pragma unroll
    for (int q=1;q<8;q++) p = cmul(p, vq[q][(h>>(7-q))&1]);
    float A = 0.f;
    #pragma unroll
    for (int kk=0;kk<7;kk++){
      int b0=(h>>(7-kk))&1, b1=(h>>(6-kk))&1;
      A += (b0==b1) ? zz0s[kk] : -zz0s[kk];
    }
    float s,c; sincosf(0.5f*A,&s,&c);
    C Vh = cmul(p, C{c,-s});
    C pl = vq[8][(h>>7)&1];
    #pragma unroll
    for (int q=9;q<16;q++) pl = cmul(pl, vq[q][(h>>(15-q))&1]);
    float Al = 0.f;
    #pragma unroll
    for (int kk=8;kk<15;kk++){
      int b0=(h>>(15-kk))&1, b1=(h>>(14-kk))&1;
      Al += (b0==b1) ? zz0s[kk] : -zz0s[kk];
    }
    sincosf(0.5f*Al,&s,&c);
    C Vl = cmul(pl, C{c,-s});
    W[0][h] = cmul(Vh, lam[0]);
    C a1 = cmul(Vh, lam[1]);
    if (h & 1){ a1.x = -a1.x; a1.y = -a1.y; }
    W[1][h] = a1;
    W[2][h] = Vl;
    W[3][h] = ((h>>7)&1) ? C{-Vl.x,-Vl.y} : Vl;
  }
  __syncthreads();                                        // B4

  // ---- conv0 rotations: 8 butterfly levels, 2 per barrier ----
  // h bit pb <-> qubit 7-pb (M0s[7-pb]); l bit pb <-> qubit 15-pb (M0s[15-pb])
  #pragma unroll
  for (int p=0; p<8; p+=2){
    int arr = tid>>6, i = tid&63;
    const C* Glo = (arr<2) ? &M0s[7-p][0]  : &M0s[15-p][0];
    const C* Ghi = (arr<2) ? &M0s[6-p][0]  : &M0s[14-p][0];
    int mp = 1<<p;
    int x = ((i>>p)<<(p+2)) | (i & (mp-1));
    C c0 = W[arr][x], c1 = W[arr][x|mp], c2 = W[arr][x|(mp<<1)], c3 = W[arr][x|mp|(mp<<1)];
    bfly(c0,c1,Glo); bfly(c2,c3,Glo);
    bfly(c0,c2,Ghi); bfly(c1,c3,Ghi);
    W[arr][x]=c0; W[arr][x|mp]=c1; W[arr][x|(mp<<1)]=c2; W[arr][x|mp|(mp<<1)]=c3;
    __syncthreads();                                      // B5..B8
  }

  // ---- Gram vectors ----
  if (tid < 32){
    int side = tid>>4, tq = tid&15;
    float g00=0.f, g11=0.f; C g01{0.f,0.f};
    #pragma unroll
    for (int kq=0;kq<16;kq++){
      int idx = expand44(tq,kq);
      C a0 = W[side*2+0][idx], a1 = W[side*2+1][idx];
      g00 += a0.x*a0.x + a0.y*a0.y;
      g11 += a1.x*a1.x + a1.y*a1.y;
      g01.x += a0.x*a1.x + a0.y*a1.y;
      g01.y += a0.y*a1.x - a0.x*a1.y;
    }
    if (side==0){ GH00[tq]=g00; GH11[tq]=g11; GH01[tq]=g01; }
    else        { GL00[tq]=g00; GL11[tq]=g11; GL01[tq]=g01; }
  }
  __syncthreads();                                        // B9

  // ---- p(t), total via wave-shuffle reduce, weights ----
  float pv;
  {
    int tH = tid>>4, tL = tid&15;
    C gh = GH01[tH], gl = GL01[tL];
    pv = GH00[tH]*GL00[tL] + GH11[tH]*GL11[tL] + 2.f*(gh.x*gl.x - gh.y*gl.y);
    pv = fmaxf(pv, 0.f);
  }
  {
    float v = pv;
    #pragma unroll
    for (int off=32; off>0; off>>=1) v += __shfl_down(v, off);
    if ((tid&63)==0) part[tid>>6] = v;
  }
  __syncthreads();                                        // B10
  {
    float tot = part[0]+part[1]+part[2]+part[3];
    w[tid] = sqrtf(pv/(tot + 1e-10f));
  }
  __syncthreads();                                        // B11

  // ---- Mx[r][tH][kL] = sum_tL w(tH,tL) * B_r(tL,kL) ----
  #pragma unroll
  for (int rep=0; rep<2; ++rep){
    int e = tid + rep*256;
    int r = e>>8, tH = (e>>4)&15, kL = e&15;
    C acc{0.f,0.f};
    #pragma unroll
    for (int tL=0;tL<16;tL++){
      float ww = w[(tH<<4)|tL];
      C bv = W[2+r][expand44(tL,kL)];
      acc.x += ww*bv.x; acc.y += ww*bv.y;
    }
    Mx[r][tH][kL] = acc;
  }
  __syncthreads();                                        // B12

  // ---- s1(k), norm via shuffle reduce ----
  C s1{0.f,0.f};
  {
    int kH = tid>>4, kL = tid&15;
    #pragma unroll
    for (int tH=0;tH<16;tH++){
      int ia = expand44(tH,kH);
      C a0 = W[0][ia], m0 = Mx[0][tH][kL];
      C a1 = W[1][ia], m1 = Mx[1][tH][kL];
      s1.x += a0.x*m0.x - a0.y*m0.y + a1.x*m1.x - a1.y*m1.y;
      s1.y += a0.x*m0.y + a0.y*m0.x + a1.x*m1.y + a1.y*m1.x;
    }
  }
  {
    float v = s1.x*s1.x + s1.y*s1.y;
    #pragma unroll
    for (int off=32; off>0; off>>=1) v += __shfl_down(v, off);
    if ((tid&63)==0) part[tid>>6] = v;
  }
  __syncthreads();                                        // B13
  {
    float n1 = sqrtf(part[0]+part[1]+part[2]+part[3] + 1e-10f);
    s1.x /= n1; s1.y /= n1;
  }
  // conv1 ZZ diagonal + store s8
  {
    float A = 0.f;
    #pragma unroll
    for (int kk=0;kk<7;kk++){
      int b0=(tid>>(7-kk))&1, b1=(tid>>(6-kk))&1;
      A += (b0==b1) ? zz1s[kk] : -zz1s[kk];
    }
    float sa,ca; sincosf(0.5f*A,&sa,&ca);
    s8[tid] = cmul(s1, C{ca,-sa});
  }
  __syncthreads();                                        // B14

  // ---- conv1: 8 levels, 2 per barrier (threads 0..63 active) ----
  // level q applies M1s[q] on bit 7-q; pair j handles (q=2j bit hb, q=2j+1 bit lb)
  #pragma unroll
  for (int j=0; j<4; ++j){
    if (tid < 64){
      int hb = 7-2*j, lb = 6-2*j;
      int ml = 1<<lb, mh = 1<<hb;
      int x = ((tid>>lb)<<(lb+1)) | (tid & (ml-1));
      x = ((x>>hb)<<(hb+1)) | (x & (mh-1));
      C c0 = s8[x], c1 = s8[x|mh], c2 = s8[x|ml], c3 = s8[x|mh|ml];
      bfly(c0,c1,&M1s[2*j][0]);   bfly(c2,c3,&M1s[2*j][0]);
      bfly(c0,c2,&M1s[2*j+1][0]); bfly(c1,c3,&M1s[2*j+1][0]);
      s8[x]=c0; s8[x|mh]=c1; s8[x|ml]=c2; s8[x|mh|ml]=c3;
    }
    __syncthreads();                                      // B15..B18
  }

  // ---- barrier-free tail in wave 0 (pool2 + measure + head), registers + shuffles ----
  if (tid < 64){
    int ld = tid & 15;
    // p2
    float p2v = 0.f;
    #pragma unroll
    for (int k2=0;k2<16;k2++){ C v=s8[expand44(ld,k2)]; p2v += v.x*v.x + v.y*v.y; }
    float S2 = p2v;
    #pragma unroll
    for (int off=1; off<16; off<<=1) S2 += __shfl_xor(S2, off);   // sum within 16-lane group
    float w2 = sqrtf(p2v/(S2 + 1e-10f));
    // s2
    C a2{0.f,0.f};
    #pragma unroll
    for (int t2=0;t2<16;t2++){
      float ww = __shfl(w2, t2);          // lanes 0..15 hold valid w2
      C v = s8[expand44(t2, ld)];
      a2.x += v.x*ww; a2.y += v.y*ww;
    }
    float nn = a2.x*a2.x + a2.y*a2.y;
    #pragma unroll
    for (int off=1; off<16; off<<=1) nn += __shfl_xor(nn, off);
    nn += 1e-10f;
    float pr = (a2.x*a2.x + a2.y*a2.y)/nn;   // lane ld represents idx=ld
    // measure_z: zm[q] = sum_idx sign(idx,q)*pr_idx  (qubit q <-> bit 3-q)
    float z0=0.f,z1=0.f,z2=0.f,z3=0.f;
    #pragma unroll
    for (int idx=0; idx<16; idx++){
      float p_ = __shfl(pr, idx);
      z0 += ((idx>>3)&1) ? -p_ : p_;
      z1 += ((idx>>2)&1) ? -p_ : p_;
      z2 += ((idx>>1)&1) ? -p_ : p_;
      z3 += ( idx     &1) ? -p_ : p_;
    }
    // head
    float r = bor + z0*wo4.x + z1*wo4.y + z2*wo4.z + z3*wo4.w;
    out[(size_t)b*64 + tid] = r;
  }
}

extern "C" void kernel_launch(void* const* d_in, const int* in_sizes, int n_in,
                              void* d_out, int out_size, void* d_ws, size_t ws_size,
                              hipStream_t stream) {
  const float* nbr  = (const float*)d_in[0];
  const float* slf  = (const float*)d_in[1];
  const float* Wp   = (const float*)d_in[2];
  const float* bp   = (const float*)d_in[3];
  const float* rot0 = (const float*)d_in[4];
  const float* zz0  = (const float*)d_in[5];
  const float* rot1 = (const float*)d_in[6];
  const float* zz1  = (const float*)d_in[7];
  const float* Wo   = (const float*)d_in[8];
  const float* bo   = (const float*)d_in[9];
  float* out = (float*)d_out;

  hipLaunchKernelGGL(k_all, dim3(NB), dim3(256), 0, stream,
                     nbr, slf, Wp, bp, rot0, zz0, rot1, zz1, Wo, bo, out);
}